// Round 1
// baseline (2978.470 us; speedup 1.0000x reference)
//
#include <hip/hip_runtime.h>
#include <math.h>

#define IN_F 512
#define C_DIM 16
#define CP 17      // C + 1 (extra attention column)
#define MPAD 20    // padded row stride for combined matrices (16B-aligned)
#define EF_DIM 64

// ---------------------------------------------------------------------------
// K0: tiny prep. Builds combined matrices and the 8-entry edge-type table.
//   Wh[k][0..15] = res_W[k][c], Wh[k][16] = wl[k] = sum_c W[k][c]*a_l[c]
//   Wt[k][0..15] = W[k][c],     Wt[k][16] = wr[k] = sum_c W[k][c]*a_r[c]
//   he[t] = sum_k emb[t][k] * v[k],  v[k] = sum_f W_e[k][f]*a_e[f]
// ---------------------------------------------------------------------------
__global__ __launch_bounds__(512) void prep_kernel(
    const float* __restrict__ W, const float* __restrict__ We,
    const float* __restrict__ al, const float* __restrict__ ar,
    const float* __restrict__ ae, const float* __restrict__ emb,
    const float* __restrict__ resW,
    float* __restrict__ Wh, float* __restrict__ Wt, float* __restrict__ he,
    int NET) {
  __shared__ float v[EF_DIM];
  int t = threadIdx.x;  // 0..511 == k index
  float wl = 0.f, wr = 0.f;
#pragma unroll
  for (int c = 0; c < C_DIM; c++) {
    float wv = W[t * C_DIM + c];
    wl += wv * al[c];
    wr += wv * ar[c];
    Wt[t * MPAD + c] = wv;
    Wh[t * MPAD + c] = resW[t * C_DIM + c];
  }
  Wh[t * MPAD + C_DIM] = wl;
  Wt[t * MPAD + C_DIM] = wr;
  if (t < EF_DIM) {
    float s = 0.f;
    for (int f = 0; f < EF_DIM; f++) s += We[t * EF_DIM + f] * ae[f];
    v[t] = s;
  }
  __syncthreads();
  if (t < NET) {
    float s = 0.f;
    for (int k = 0; k < EF_DIM; k++) s += emb[t * EF_DIM + k] * v[k];
    he[t] = s;
  }
}

// ---------------------------------------------------------------------------
// K1/K2: skinny GEMM  out[N][17] = feat[N][512] @ M[512][17]
// thread-per-row; row streamed as float4; M indices are wave-uniform
// (compiler emits s_load; M is L2-resident, ~40KB).
// ---------------------------------------------------------------------------
__global__ __launch_bounds__(256) void proj_kernel(
    const float* __restrict__ feat, const float* __restrict__ M,
    float* __restrict__ out16, float* __restrict__ out1, int N) {
  int r = blockIdx.x * blockDim.x + threadIdx.x;
  if (r >= N) return;
  const float4* x = (const float4*)(feat + (size_t)r * IN_F);
  float acc[CP];
#pragma unroll
  for (int c = 0; c < CP; c++) acc[c] = 0.f;
#pragma unroll 2
  for (int j = 0; j < IN_F / 4; j++) {
    float4 xv = x[j];
    const float* m0 = M + (size_t)(4 * j) * MPAD;
#pragma unroll
    for (int c = 0; c < CP; c++) acc[c] += xv.x * m0[c];
#pragma unroll
    for (int c = 0; c < CP; c++) acc[c] += xv.y * m0[MPAD + c];
#pragma unroll
    for (int c = 0; c < CP; c++) acc[c] += xv.z * m0[2 * MPAD + c];
#pragma unroll
    for (int c = 0; c < CP; c++) acc[c] += xv.w * m0[3 * MPAD + c];
  }
  float4* o = (float4*)(out16 + (size_t)r * C_DIM);
  o[0] = make_float4(acc[0], acc[1], acc[2], acc[3]);
  o[1] = make_float4(acc[4], acc[5], acc[6], acc[7]);
  o[2] = make_float4(acc[8], acc[9], acc[10], acc[11]);
  o[3] = make_float4(acc[12], acc[13], acc[14], acc[15]);
  out1[r] = acc[16];
}

// ---------------------------------------------------------------------------
// K3: edge pass. logit -> leaky_relu -> exp (no max subtraction: logits are
// bounded ~|12|, safe in f32 and mathematically identical after the divide).
// Accumulate unnormalized numerator and denominator with atomics.
// ---------------------------------------------------------------------------
__global__ __launch_bounds__(256) void edge_kernel(
    const int* __restrict__ head, const int* __restrict__ tail,
    const int* __restrict__ ty, const float* __restrict__ h_l,
    const float* __restrict__ h_r, const float* __restrict__ he,
    const float* __restrict__ ht16, float* __restrict__ denom,
    float* __restrict__ unorm, int E) {
  int e = blockIdx.x * blockDim.x + threadIdx.x;
  if (e >= E) return;
  int h = head[e];
  int t = tail[e];
  int k = ty[e];
  float lg = h_l[h] + h_r[t] + he[k];
  lg = lg > 0.f ? lg : 0.2f * lg;
  float ex = __expf(lg);
  atomicAdd(denom + h, ex);
  const float4* hv = (const float4*)(ht16 + (size_t)t * C_DIM);
  float* up = unorm + (size_t)h * C_DIM;
#pragma unroll
  for (int q = 0; q < 4; q++) {
    float4 xv = hv[q];
    atomicAdd(up + 4 * q + 0, ex * xv.x);
    atomicAdd(up + 4 * q + 1, ex * xv.y);
    atomicAdd(up + 4 * q + 2, ex * xv.z);
    atomicAdd(up + 4 * q + 3, ex * xv.w);
  }
}

// ---------------------------------------------------------------------------
// K4: finalize per node: out = unorm/denom + resid + res_b; L2-normalize row;
// softmax over the 16 columns.
// ---------------------------------------------------------------------------
__global__ __launch_bounds__(256) void final_kernel(
    const float* __restrict__ unorm, const float* __restrict__ denom,
    const float* __restrict__ resid, const float* __restrict__ resb,
    float* __restrict__ out, int N) {
  int i = blockIdx.x * blockDim.x + threadIdx.x;
  if (i >= N) return;
  float d = denom[i];
  float inv = d > 0.f ? 1.f / d : 0.f;
  const float4* u4 = (const float4*)(unorm + (size_t)i * C_DIM);
  const float4* r4 = (const float4*)(resid + (size_t)i * C_DIM);
  float o[C_DIM];
  float ss = 0.f;
#pragma unroll
  for (int q = 0; q < 4; q++) {
    float4 u = u4[q];
    float4 rr = r4[q];
    o[4 * q + 0] = u.x * inv + rr.x + resb[4 * q + 0];
    o[4 * q + 1] = u.y * inv + rr.y + resb[4 * q + 1];
    o[4 * q + 2] = u.z * inv + rr.z + resb[4 * q + 2];
    o[4 * q + 3] = u.w * inv + rr.w + resb[4 * q + 3];
  }
#pragma unroll
  for (int c = 0; c < C_DIM; c++) ss += o[c] * o[c];
  float nrm = sqrtf(ss);
  float s = 1.f / fmaxf(nrm, 1e-12f);
  float mx = -1e30f;
#pragma unroll
  for (int c = 0; c < C_DIM; c++) {
    o[c] *= s;
    mx = fmaxf(mx, o[c]);
  }
  float sum = 0.f;
#pragma unroll
  for (int c = 0; c < C_DIM; c++) {
    o[c] = __expf(o[c] - mx);
    sum += o[c];
  }
  float isum = 1.f / sum;
  float4* o4 = (float4*)(out + (size_t)i * C_DIM);
#pragma unroll
  for (int q = 0; q < 4; q++)
    o4[q] = make_float4(o[4 * q] * isum, o[4 * q + 1] * isum,
                        o[4 * q + 2] * isum, o[4 * q + 3] * isum);
}

// ---------------------------------------------------------------------------
extern "C" void kernel_launch(void* const* d_in, const int* in_sizes, int n_in,
                              void* d_out, int out_size, void* d_ws,
                              size_t ws_size, hipStream_t stream) {
  const float* head_feature = (const float*)d_in[0];
  const float* tail_feature = (const float*)d_in[1];
  const int* edge_index = (const int*)d_in[2];
  const int* tmp_edge = (const int*)d_in[3];
  const float* W = (const float*)d_in[4];
  const float* We = (const float*)d_in[5];
  const float* al = (const float*)d_in[6];
  const float* ar = (const float*)d_in[7];
  const float* ae = (const float*)d_in[8];
  const float* emb = (const float*)d_in[9];
  const float* resW = (const float*)d_in[10];
  const float* resb = (const float*)d_in[11];

  const int C = in_sizes[6];            // 16
  const int IN = in_sizes[4] / C;       // 512
  const int N = in_sizes[0] / IN;       // 100000
  const int E = in_sizes[3];            // 3200000
  const int EF = in_sizes[8];           // 64
  const int NET = in_sizes[9] / EF;     // 8
  (void)C; (void)IN; (void)ws_size; (void)out_size; (void)n_in;

  const int* head = edge_index;
  const int* tail = edge_index + E;

  float* ws = (float*)d_ws;
  float* Wh = ws;                         // 512*20
  float* Wt = Wh + IN_F * MPAD;           // 512*20
  float* he = Wt + IN_F * MPAD;           // 32
  float* base = he + 32;
  float* h_l = base;                      // N
  float* h_r = h_l + N;                   // N
  float* dn = h_r + N;                    // N
  float* un = dn + N;                     // 16N  (dn..un contiguous -> 1 memset)
  float* resid = un + (size_t)C_DIM * N;  // 16N
  float* ht = resid + (size_t)C_DIM * N;  // 16N

  // zero the atomic accumulators (denom + unorm, contiguous 17N floats)
  hipMemsetAsync(dn, 0, (size_t)(C_DIM + 1) * N * sizeof(float), stream);

  prep_kernel<<<1, 512, 0, stream>>>(W, We, al, ar, ae, emb, resW, Wh, Wt, he,
                                     NET);
  int nb = (N + 255) / 256;
  proj_kernel<<<nb, 256, 0, stream>>>(head_feature, Wh, resid, h_l, N);
  proj_kernel<<<nb, 256, 0, stream>>>(tail_feature, Wt, ht, h_r, N);
  edge_kernel<<<(E + 255) / 256, 256, 0, stream>>>(head, tail, tmp_edge, h_l,
                                                   h_r, he, ht, dn, un, E);
  final_kernel<<<nb, 256, 0, stream>>>(un, dn, resid, resb, (float*)d_out, N);
}

// Round 2
// 661.539 us; speedup vs baseline: 4.5023x; 4.5023x over previous
//
#include <hip/hip_runtime.h>
#include <math.h>

#define IN_F 512
#define C_DIM 16
#define CP 17      // C + 1 (extra attention column)
#define MPAD 20    // padded row stride for combined matrices (16B-aligned)
#define EF_DIM 64
#define NPB 256    // nodes per bucket (node>>8). local id fits in 8 bits
#define NBMAX 512  // max buckets (N<=131072 also keeps tail in 17 bits)
#define ACCW 17    // LDS accumulator row stride (odd -> spread banks)

// ---------------------------------------------------------------------------
// K0: tiny prep. Builds combined matrices and the 8-entry edge-type table.
//   Wh[k][0..15] = res_W[k][c], Wh[k][16] = wl[k] = sum_c W[k][c]*a_l[c]
//   Wt[k][0..15] = W[k][c],     Wt[k][16] = wr[k] = sum_c W[k][c]*a_r[c]
//   he[t] = sum_k emb[t][k] * v[k],  v[k] = sum_f W_e[k][f]*a_e[f]
// ---------------------------------------------------------------------------
__global__ __launch_bounds__(512) void prep_kernel(
    const float* __restrict__ W, const float* __restrict__ We,
    const float* __restrict__ al, const float* __restrict__ ar,
    const float* __restrict__ ae, const float* __restrict__ emb,
    const float* __restrict__ resW,
    float* __restrict__ Wh, float* __restrict__ Wt, float* __restrict__ he,
    int NET) {
  __shared__ float v[EF_DIM];
  int t = threadIdx.x;  // 0..511 == k index
  float wl = 0.f, wr = 0.f;
#pragma unroll
  for (int c = 0; c < C_DIM; c++) {
    float wv = W[t * C_DIM + c];
    wl += wv * al[c];
    wr += wv * ar[c];
    Wt[t * MPAD + c] = wv;
    Wh[t * MPAD + c] = resW[t * C_DIM + c];
  }
  Wh[t * MPAD + C_DIM] = wl;
  Wt[t * MPAD + C_DIM] = wr;
  if (t < EF_DIM) {
    float s = 0.f;
    for (int f = 0; f < EF_DIM; f++) s += We[t * EF_DIM + f] * ae[f];
    v[t] = s;
  }
  __syncthreads();
  if (t < NET) {
    float s = 0.f;
    for (int k = 0; k < EF_DIM; k++) s += emb[t * EF_DIM + k] * v[k];
    he[t] = s;
  }
}

// ---------------------------------------------------------------------------
// K1/K2: skinny GEMM  out[N][17] = feat[N][512] @ M[512][17]
// thread-per-row; row streamed as float4; M indices are wave-uniform.
// ---------------------------------------------------------------------------
__global__ __launch_bounds__(256) void proj_kernel(
    const float* __restrict__ feat, const float* __restrict__ M,
    float* __restrict__ out16, float* __restrict__ out1, int N) {
  int r = blockIdx.x * blockDim.x + threadIdx.x;
  if (r >= N) return;
  const float4* x = (const float4*)(feat + (size_t)r * IN_F);
  float acc[CP];
#pragma unroll
  for (int c = 0; c < CP; c++) acc[c] = 0.f;
#pragma unroll 2
  for (int j = 0; j < IN_F / 4; j++) {
    float4 xv = x[j];
    const float* m0 = M + (size_t)(4 * j) * MPAD;
#pragma unroll
    for (int c = 0; c < CP; c++) acc[c] += xv.x * m0[c];
#pragma unroll
    for (int c = 0; c < CP; c++) acc[c] += xv.y * m0[MPAD + c];
#pragma unroll
    for (int c = 0; c < CP; c++) acc[c] += xv.z * m0[2 * MPAD + c];
#pragma unroll
    for (int c = 0; c < CP; c++) acc[c] += xv.w * m0[3 * MPAD + c];
  }
  float4* o = (float4*)(out16 + (size_t)r * C_DIM);
  o[0] = make_float4(acc[0], acc[1], acc[2], acc[3]);
  o[1] = make_float4(acc[4], acc[5], acc[6], acc[7]);
  o[2] = make_float4(acc[8], acc[9], acc[10], acc[11]);
  o[3] = make_float4(acc[12], acc[13], acc[14], acc[15]);
  out1[r] = acc[16];
}

// ---------------------------------------------------------------------------
// K3: per-bucket histogram of head ids. LDS-aggregated; ~NB global int
// atomics per block (vs 17 float atomics per EDGE before).
// ---------------------------------------------------------------------------
__global__ __launch_bounds__(256) void hist_kernel(
    const int* __restrict__ head, unsigned* __restrict__ btotal, int E, int NB,
    int chunk) {
  __shared__ unsigned lcnt[NBMAX];
  int tid = threadIdx.x;
  for (int b = tid; b < NB; b += 256) lcnt[b] = 0u;
  __syncthreads();
  int start = blockIdx.x * chunk;
  int end = min(E, start + chunk);
  for (int i = start + tid; i < end; i += 256)
    atomicAdd(&lcnt[((unsigned)head[i]) >> 8], 1u);
  __syncthreads();
  for (int b = tid; b < NB; b += 256) {
    unsigned c = lcnt[b];
    if (c) atomicAdd(&btotal[b], c);
  }
}

// ---------------------------------------------------------------------------
// K4: exclusive scan of bucket totals (NB <= 512, one block).
// base[NB] gets the grand total E. cursor = working copy for scatter.
// ---------------------------------------------------------------------------
__global__ __launch_bounds__(512) void scan_kernel(
    const unsigned* __restrict__ btotal, unsigned* __restrict__ base,
    unsigned* __restrict__ cursor, int NB) {
  __shared__ unsigned s[512];
  int t = threadIdx.x;
  unsigned orig = (t < NB) ? btotal[t] : 0u;
  s[t] = orig;
  __syncthreads();
  for (int off = 1; off < 512; off <<= 1) {
    unsigned v = (t >= off) ? s[t - off] : 0u;
    __syncthreads();
    s[t] += v;
    __syncthreads();
  }
  if (t < NB) {
    unsigned b0 = s[t] - orig;
    base[t] = b0;
    cursor[t] = b0;
    if (t == NB - 1) base[NB] = s[t];
  }
}

// ---------------------------------------------------------------------------
// K5: counting-sort scatter. Per-block LDS histogram -> one cursor
// reservation per (block,bucket) -> LDS-atomic slot assignment. Packs each
// edge into 4 bytes: local(8) | type(3) | tail(17).
// ---------------------------------------------------------------------------
__global__ __launch_bounds__(256) void scatter_kernel(
    const int* __restrict__ head, const int* __restrict__ tail,
    const int* __restrict__ ty, unsigned* __restrict__ cursor,
    unsigned* __restrict__ rec, int E, int NB, int chunk) {
  __shared__ unsigned lcnt[NBMAX];
  __shared__ unsigned lbase[NBMAX];
  int tid = threadIdx.x;
  for (int b = tid; b < NB; b += 256) lcnt[b] = 0u;
  __syncthreads();
  int start = blockIdx.x * chunk;
  int end = min(E, start + chunk);
  for (int i = start + tid; i < end; i += 256)
    atomicAdd(&lcnt[((unsigned)head[i]) >> 8], 1u);
  __syncthreads();
  for (int b = tid; b < NB; b += 256) {
    unsigned c = lcnt[b];
    lbase[b] = c ? atomicAdd(&cursor[b], c) : 0u;
  }
  __syncthreads();
  for (int b = tid; b < NB; b += 256) lcnt[b] = 0u;
  __syncthreads();
  for (int i = start + tid; i < end; i += 256) {
    unsigned h = (unsigned)head[i];
    unsigned b = h >> 8;
    unsigned off = atomicAdd(&lcnt[b], 1u);
    rec[lbase[b] + off] =
        ((h & 255u) << 20) | (((unsigned)ty[i] & 7u) << 17) | (unsigned)tail[i];
  }
}

// ---------------------------------------------------------------------------
// K6: per-bucket aggregation in LDS + fused finalize.
// 16 lanes cooperate per edge: lane c handles channel c -> ht row gather is
// one coalesced 64B line; accumulation via ds_add_f32 (no global atomics).
// Epilogue: divide by denom, residual add, L2-normalize, softmax-16, store.
// ---------------------------------------------------------------------------
__global__ __launch_bounds__(256) void agg_kernel(
    const unsigned* __restrict__ rec, const unsigned* __restrict__ base,
    const float* __restrict__ h_l, const float* __restrict__ h_r,
    const float* __restrict__ he_tab, const float* __restrict__ ht,
    const float* __restrict__ resid, const float* __restrict__ resb,
    float* __restrict__ out, int N, int NET) {
  __shared__ float acc[NPB * ACCW];
  __shared__ float he_s[32];
  int tid = threadIdx.x;
  if (tid < NET) he_s[tid] = he_tab[tid];
  for (int i = tid; i < NPB * ACCW; i += 256) acc[i] = 0.f;
  __syncthreads();
  int b = blockIdx.x;
  int s = (int)base[b];
  int e = (int)base[b + 1];
  int lane = tid & 63;
  int wid = tid >> 6;
  int c = lane & 15;
  int sub = lane >> 4;  // 4 edges per wave iteration
  int nodebase = b << 8;
  for (int i = s + wid * 4 + sub; i < e; i += 16) {
    unsigned r = rec[i];
    int local = (int)(r >> 20);
    int typ = (int)((r >> 17) & 7u);
    int tl = (int)(r & 0x1FFFFu);
    float lg = h_l[nodebase + local] + h_r[tl] + he_s[typ];
    lg = lg > 0.f ? lg : 0.2f * lg;
    float ex = __expf(lg);
    atomicAdd(&acc[local * ACCW + c], ex * ht[(size_t)tl * C_DIM + c]);
    if (c == 0) atomicAdd(&acc[local * ACCW + 16], ex);
  }
  __syncthreads();
  int node = nodebase + tid;
  if (node >= N) return;
  float d = acc[tid * ACCW + 16];
  float inv = d > 0.f ? 1.f / d : 0.f;
  const float4* r4 = (const float4*)(resid + (size_t)node * C_DIM);
  float o[C_DIM];
  float ss = 0.f;
#pragma unroll
  for (int q = 0; q < 4; q++) {
    float4 rr = r4[q];
    o[4 * q + 0] = acc[tid * ACCW + 4 * q + 0] * inv + rr.x + resb[4 * q + 0];
    o[4 * q + 1] = acc[tid * ACCW + 4 * q + 1] * inv + rr.y + resb[4 * q + 1];
    o[4 * q + 2] = acc[tid * ACCW + 4 * q + 2] * inv + rr.z + resb[4 * q + 2];
    o[4 * q + 3] = acc[tid * ACCW + 4 * q + 3] * inv + rr.w + resb[4 * q + 3];
  }
#pragma unroll
  for (int cc = 0; cc < C_DIM; cc++) ss += o[cc] * o[cc];
  float sc = 1.f / fmaxf(sqrtf(ss), 1e-12f);
  float mx = -1e30f;
#pragma unroll
  for (int cc = 0; cc < C_DIM; cc++) {
    o[cc] *= sc;
    mx = fmaxf(mx, o[cc]);
  }
  float sum = 0.f;
#pragma unroll
  for (int cc = 0; cc < C_DIM; cc++) {
    o[cc] = __expf(o[cc] - mx);
    sum += o[cc];
  }
  float isum = 1.f / sum;
  float4* o4 = (float4*)(out + (size_t)node * C_DIM);
#pragma unroll
  for (int q = 0; q < 4; q++)
    o4[q] = make_float4(o[4 * q] * isum, o[4 * q + 1] * isum,
                        o[4 * q + 2] * isum, o[4 * q + 3] * isum);
}

// ---------------------------------------------------------------------------
extern "C" void kernel_launch(void* const* d_in, const int* in_sizes, int n_in,
                              void* d_out, int out_size, void* d_ws,
                              size_t ws_size, hipStream_t stream) {
  const float* head_feature = (const float*)d_in[0];
  const float* tail_feature = (const float*)d_in[1];
  const int* edge_index = (const int*)d_in[2];
  const int* tmp_edge = (const int*)d_in[3];
  const float* W = (const float*)d_in[4];
  const float* We = (const float*)d_in[5];
  const float* al = (const float*)d_in[6];
  const float* ar = (const float*)d_in[7];
  const float* ae = (const float*)d_in[8];
  const float* emb = (const float*)d_in[9];
  const float* resW = (const float*)d_in[10];
  const float* resb = (const float*)d_in[11];

  const int C = in_sizes[6];         // 16
  const int IN = in_sizes[4] / C;    // 512
  const int N = in_sizes[0] / IN;    // 100000
  const int E = in_sizes[3];         // 3200000
  const int EF = in_sizes[8];        // 64
  const int NET = in_sizes[9] / EF;  // 8
  const int NB = (N + NPB - 1) / NPB;  // 391
  (void)C; (void)IN; (void)EF; (void)ws_size; (void)out_size; (void)n_in;

  const int* head = edge_index;
  const int* tail = edge_index + E;

  float* ws = (float*)d_ws;
  float* Wh = ws;                            // 512*20
  float* Wt = Wh + IN_F * MPAD;              // 512*20
  float* he = Wt + IN_F * MPAD;              // 32
  float* h_l = he + 32;                      // N
  float* h_r = h_l + N;                      // N
  float* ht = h_r + N;                       // 16N (64B-aligned rows)
  float* resid = ht + (size_t)C_DIM * N;     // 16N
  unsigned* rec = (unsigned*)(resid + (size_t)C_DIM * N);  // E
  unsigned* btotal = rec + E;                // NBMAX
  unsigned* bbase = btotal + NBMAX;          // NBMAX+1
  unsigned* cursor = bbase + NBMAX + 1;      // NBMAX

  // only per-call zeroing needed: bucket totals (2KB)
  hipMemsetAsync(btotal, 0, NBMAX * sizeof(unsigned), stream);

  prep_kernel<<<1, 512, 0, stream>>>(W, We, al, ar, ae, emb, resW, Wh, Wt, he,
                                     NET);
  int nb = (N + 255) / 256;
  proj_kernel<<<nb, 256, 0, stream>>>(head_feature, Wh, resid, h_l, N);
  proj_kernel<<<nb, 256, 0, stream>>>(tail_feature, Wt, ht, h_r, N);

  int chunk = (E + 255) / 256;  // 256 partition blocks
  hist_kernel<<<256, 256, 0, stream>>>(head, btotal, E, NB, chunk);
  scan_kernel<<<1, 512, 0, stream>>>(btotal, bbase, cursor, NB);
  scatter_kernel<<<256, 256, 0, stream>>>(head, tail, tmp_edge, cursor, rec, E,
                                          NB, chunk);
  agg_kernel<<<NB, 256, 0, stream>>>(rec, bbase, h_l, h_r, he, ht, resid, resb,
                                     (float*)d_out, N, NET);
}

// Round 3
// 606.816 us; speedup vs baseline: 4.9084x; 1.0902x over previous
//
#include <hip/hip_runtime.h>
#include <math.h>

#define IN_F 512
#define C_DIM 16
#define CP 17      // C + 1 (extra attention column)
#define MPAD 20    // padded row stride for combined matrices (16B-aligned)
#define EF_DIM 64
#define BSHIFT 6   // nodes-per-bucket shift
#define NPB 64     // nodes per bucket (node>>6). local id fits in 6 bits
#define NBMAX2 2048  // max buckets (N <= 131072: tail fits 17 bits too)
#define ACCW 17    // LDS accumulator row stride (odd -> spread banks)

// record layout: local(6) [20:25] | type(3) [17:19] | tail(17) [0:16]

// ---------------------------------------------------------------------------
// K0: tiny prep. Builds combined matrices and the 8-entry edge-type table.
// ---------------------------------------------------------------------------
__global__ __launch_bounds__(512) void prep_kernel(
    const float* __restrict__ W, const float* __restrict__ We,
    const float* __restrict__ al, const float* __restrict__ ar,
    const float* __restrict__ ae, const float* __restrict__ emb,
    const float* __restrict__ resW,
    float* __restrict__ Wh, float* __restrict__ Wt, float* __restrict__ he,
    int NET) {
  __shared__ float v[EF_DIM];
  int t = threadIdx.x;  // 0..511 == k index
  float wl = 0.f, wr = 0.f;
#pragma unroll
  for (int c = 0; c < C_DIM; c++) {
    float wv = W[t * C_DIM + c];
    wl += wv * al[c];
    wr += wv * ar[c];
    Wt[t * MPAD + c] = wv;
    Wh[t * MPAD + c] = resW[t * C_DIM + c];
  }
  Wh[t * MPAD + C_DIM] = wl;
  Wt[t * MPAD + C_DIM] = wr;
  if (t < EF_DIM) {
    float s = 0.f;
    for (int f = 0; f < EF_DIM; f++) s += We[t * EF_DIM + f] * ae[f];
    v[t] = s;
  }
  __syncthreads();
  if (t < NET) {
    float s = 0.f;
    for (int k = 0; k < EF_DIM; k++) s += emb[t * EF_DIM + k] * v[k];
    he[t] = s;
  }
}

// ---------------------------------------------------------------------------
// K1/K2: skinny GEMM  out[N][17] = feat[N][512] @ M[512][17]
// ---------------------------------------------------------------------------
__global__ __launch_bounds__(256) void proj_kernel(
    const float* __restrict__ feat, const float* __restrict__ M,
    float* __restrict__ out16, float* __restrict__ out1, int N) {
  int r = blockIdx.x * blockDim.x + threadIdx.x;
  if (r >= N) return;
  const float4* x = (const float4*)(feat + (size_t)r * IN_F);
  float acc[CP];
#pragma unroll
  for (int c = 0; c < CP; c++) acc[c] = 0.f;
#pragma unroll 2
  for (int j = 0; j < IN_F / 4; j++) {
    float4 xv = x[j];
    const float* m0 = M + (size_t)(4 * j) * MPAD;
#pragma unroll
    for (int c = 0; c < CP; c++) acc[c] += xv.x * m0[c];
#pragma unroll
    for (int c = 0; c < CP; c++) acc[c] += xv.y * m0[MPAD + c];
#pragma unroll
    for (int c = 0; c < CP; c++) acc[c] += xv.z * m0[2 * MPAD + c];
#pragma unroll
    for (int c = 0; c < CP; c++) acc[c] += xv.w * m0[3 * MPAD + c];
  }
  float4* o = (float4*)(out16 + (size_t)r * C_DIM);
  o[0] = make_float4(acc[0], acc[1], acc[2], acc[3]);
  o[1] = make_float4(acc[4], acc[5], acc[6], acc[7]);
  o[2] = make_float4(acc[8], acc[9], acc[10], acc[11]);
  o[3] = make_float4(acc[12], acc[13], acc[14], acc[15]);
  out1[r] = acc[16];
}

// ---------------------------------------------------------------------------
// K3: per-bucket histogram of head ids (bucket = head >> 6).
// ---------------------------------------------------------------------------
__global__ __launch_bounds__(256) void hist_kernel(
    const int* __restrict__ head, unsigned* __restrict__ btotal, int E, int NB,
    int chunk) {
  __shared__ unsigned lcnt[NBMAX2];
  int tid = threadIdx.x;
  for (int b = tid; b < NB; b += 256) lcnt[b] = 0u;
  __syncthreads();
  int start = blockIdx.x * chunk;
  int end = min(E, start + chunk);
  for (int i = start + tid; i < end; i += 256)
    atomicAdd(&lcnt[((unsigned)head[i]) >> BSHIFT], 1u);
  __syncthreads();
  for (int b = tid; b < NB; b += 256) {
    unsigned c = lcnt[b];
    if (c) atomicAdd(&btotal[b], c);
  }
}

// ---------------------------------------------------------------------------
// K4: exclusive scan of bucket totals. 1024 threads x 2 elements -> up to
// 2048 buckets in one block. base[NB] gets the grand total E.
// ---------------------------------------------------------------------------
__global__ __launch_bounds__(1024) void scan_kernel(
    const unsigned* __restrict__ btotal, unsigned* __restrict__ base,
    unsigned* __restrict__ cursor, int NB) {
  __shared__ unsigned ps[1024];
  int t = threadIdx.x;
  unsigned a = (2 * t < NB) ? btotal[2 * t] : 0u;
  unsigned b = (2 * t + 1 < NB) ? btotal[2 * t + 1] : 0u;
  ps[t] = a + b;
  __syncthreads();
  for (int off = 1; off < 1024; off <<= 1) {
    unsigned v = (t >= off) ? ps[t - off] : 0u;
    __syncthreads();
    ps[t] += v;
    __syncthreads();
  }
  unsigned excl = ps[t] - (a + b);  // exclusive over this thread's pair
  if (2 * t < NB) {
    base[2 * t] = excl;
    cursor[2 * t] = excl;
  }
  if (2 * t + 1 < NB) {
    base[2 * t + 1] = excl + a;
    cursor[2 * t + 1] = excl + a;
  }
  if (t == 1023) base[NB] = ps[1023];
}

// ---------------------------------------------------------------------------
// K5: counting-sort scatter into packed 4-byte records.
// ---------------------------------------------------------------------------
__global__ __launch_bounds__(256) void scatter_kernel(
    const int* __restrict__ head, const int* __restrict__ tail,
    const int* __restrict__ ty, unsigned* __restrict__ cursor,
    unsigned* __restrict__ rec, int E, int NB, int chunk) {
  __shared__ unsigned lcnt[NBMAX2];
  __shared__ unsigned lbase[NBMAX2];
  int tid = threadIdx.x;
  for (int b = tid; b < NB; b += 256) lcnt[b] = 0u;
  __syncthreads();
  int start = blockIdx.x * chunk;
  int end = min(E, start + chunk);
  for (int i = start + tid; i < end; i += 256)
    atomicAdd(&lcnt[((unsigned)head[i]) >> BSHIFT], 1u);
  __syncthreads();
  for (int b = tid; b < NB; b += 256) {
    unsigned c = lcnt[b];
    lbase[b] = c ? atomicAdd(&cursor[b], c) : 0u;
  }
  __syncthreads();
  for (int b = tid; b < NB; b += 256) lcnt[b] = 0u;
  __syncthreads();
  for (int i = start + tid; i < end; i += 256) {
    unsigned h = (unsigned)head[i];
    unsigned b = h >> BSHIFT;
    unsigned off = atomicAdd(&lcnt[b], 1u);
    rec[lbase[b] + off] = ((h & 63u) << 20) | (((unsigned)ty[i] & 7u) << 17) |
                          (unsigned)tail[i];
  }
}

// ---------------------------------------------------------------------------
// K6: per-bucket aggregation in LDS + fused finalize. 16 lanes per edge:
// lane c handles channel c -> one coalesced 64B ht row per edge.
// NPB=64 -> 1563 blocks -> ~24 waves/CU to hide gather latency.
// ---------------------------------------------------------------------------
__global__ __launch_bounds__(256) void agg_kernel(
    const unsigned* __restrict__ rec, const unsigned* __restrict__ base,
    const float* __restrict__ h_l, const float* __restrict__ h_r,
    const float* __restrict__ he_tab, const float* __restrict__ ht,
    const float* __restrict__ resid, const float* __restrict__ resb,
    float* __restrict__ out, int N, int NET) {
  __shared__ float acc[NPB * ACCW];
  __shared__ float he_s[32];
  int tid = threadIdx.x;
  if (tid < NET) he_s[tid] = he_tab[tid];
  for (int i = tid; i < NPB * ACCW; i += 256) acc[i] = 0.f;
  __syncthreads();
  int b = blockIdx.x;
  int s = (int)base[b];
  int e = (int)base[b + 1];
  int lane = tid & 63;
  int wid = tid >> 6;
  int c = lane & 15;
  int sub = lane >> 4;  // 4 edges per wave iteration, 16 per block iteration
  int nodebase = b << BSHIFT;
  for (int i = s + wid * 4 + sub; i < e; i += 16) {
    unsigned r = rec[i];
    int local = (int)(r >> 20);
    int typ = (int)((r >> 17) & 7u);
    int tl = (int)(r & 0x1FFFFu);
    float lg = h_l[nodebase + local] + h_r[tl] + he_s[typ];
    lg = lg > 0.f ? lg : 0.2f * lg;
    float ex = __expf(lg);
    atomicAdd(&acc[local * ACCW + c], ex * ht[(size_t)tl * C_DIM + c]);
    if (c == 0) atomicAdd(&acc[local * ACCW + 16], ex);
  }
  __syncthreads();
  if (tid >= NPB) return;
  int node = nodebase + tid;
  if (node >= N) return;
  float d = acc[tid * ACCW + 16];
  float inv = d > 0.f ? 1.f / d : 0.f;
  const float4* r4 = (const float4*)(resid + (size_t)node * C_DIM);
  float o[C_DIM];
  float ss = 0.f;
#pragma unroll
  for (int q = 0; q < 4; q++) {
    float4 rr = r4[q];
    o[4 * q + 0] = acc[tid * ACCW + 4 * q + 0] * inv + rr.x + resb[4 * q + 0];
    o[4 * q + 1] = acc[tid * ACCW + 4 * q + 1] * inv + rr.y + resb[4 * q + 1];
    o[4 * q + 2] = acc[tid * ACCW + 4 * q + 2] * inv + rr.z + resb[4 * q + 2];
    o[4 * q + 3] = acc[tid * ACCW + 4 * q + 3] * inv + rr.w + resb[4 * q + 3];
  }
#pragma unroll
  for (int cc = 0; cc < C_DIM; cc++) ss += o[cc] * o[cc];
  float sc = 1.f / fmaxf(sqrtf(ss), 1e-12f);
  float mx = -1e30f;
#pragma unroll
  for (int cc = 0; cc < C_DIM; cc++) {
    o[cc] *= sc;
    mx = fmaxf(mx, o[cc]);
  }
  float sum = 0.f;
#pragma unroll
  for (int cc = 0; cc < C_DIM; cc++) {
    o[cc] = __expf(o[cc] - mx);
    sum += o[cc];
  }
  float isum = 1.f / sum;
  float4* o4 = (float4*)(out + (size_t)node * C_DIM);
#pragma unroll
  for (int q = 0; q < 4; q++)
    o4[q] = make_float4(o[4 * q] * isum, o[4 * q + 1] * isum,
                        o[4 * q + 2] * isum, o[4 * q + 3] * isum);
}

// ---------------------------------------------------------------------------
extern "C" void kernel_launch(void* const* d_in, const int* in_sizes, int n_in,
                              void* d_out, int out_size, void* d_ws,
                              size_t ws_size, hipStream_t stream) {
  const float* head_feature = (const float*)d_in[0];
  const float* tail_feature = (const float*)d_in[1];
  const int* edge_index = (const int*)d_in[2];
  const int* tmp_edge = (const int*)d_in[3];
  const float* W = (const float*)d_in[4];
  const float* We = (const float*)d_in[5];
  const float* al = (const float*)d_in[6];
  const float* ar = (const float*)d_in[7];
  const float* ae = (const float*)d_in[8];
  const float* emb = (const float*)d_in[9];
  const float* resW = (const float*)d_in[10];
  const float* resb = (const float*)d_in[11];

  const int C = in_sizes[6];           // 16
  const int IN = in_sizes[4] / C;      // 512
  const int N = in_sizes[0] / IN;      // 100000
  const int E = in_sizes[3];           // 3200000
  const int EF = in_sizes[8];          // 64
  const int NET = in_sizes[9] / EF;    // 8
  const int NB = (N + NPB - 1) / NPB;  // 1563
  (void)C; (void)IN; (void)EF; (void)ws_size; (void)out_size; (void)n_in;

  const int* head = edge_index;
  const int* tail = edge_index + E;

  float* ws = (float*)d_ws;
  float* Wh = ws;                            // 512*20
  float* Wt = Wh + IN_F * MPAD;              // 512*20
  float* he = Wt + IN_F * MPAD;              // 32
  float* h_l = he + 32;                      // N
  float* h_r = h_l + N;                      // N
  float* ht = h_r + N;                       // 16N (64B-aligned rows)
  float* resid = ht + (size_t)C_DIM * N;     // 16N
  unsigned* rec = (unsigned*)(resid + (size_t)C_DIM * N);  // E
  unsigned* btotal = rec + E;                // NBMAX2
  unsigned* bbase = btotal + NBMAX2;         // NBMAX2+1
  unsigned* cursor = bbase + NBMAX2 + 1;     // NBMAX2

  // only per-call zeroing needed: bucket totals (8KB)
  hipMemsetAsync(btotal, 0, NBMAX2 * sizeof(unsigned), stream);

  prep_kernel<<<1, 512, 0, stream>>>(W, We, al, ar, ae, emb, resW, Wh, Wt, he,
                                     NET);
  int nb = (N + 255) / 256;
  proj_kernel<<<nb, 256, 0, stream>>>(head_feature, Wh, resid, h_l, N);
  proj_kernel<<<nb, 256, 0, stream>>>(tail_feature, Wt, ht, h_r, N);

  int chunk = (E + 255) / 256;  // 256 partition blocks
  hist_kernel<<<256, 256, 0, stream>>>(head, btotal, E, NB, chunk);
  scan_kernel<<<1, 1024, 0, stream>>>(btotal, bbase, cursor, NB);
  scatter_kernel<<<256, 256, 0, stream>>>(head, tail, tmp_edge, cursor, rec, E,
                                          NB, chunk);
  agg_kernel<<<NB, 256, 0, stream>>>(rec, bbase, h_l, h_r, he, ht, resid, resb,
                                     (float*)d_out, N, NET);
}

// Round 4
// 606.511 us; speedup vs baseline: 4.9108x; 1.0005x over previous
//
#include <hip/hip_runtime.h>
#include <math.h>

#define IN_F 512
#define C_DIM 16
#define CP 17        // C + 1 (extra attention column)
#define MPAD 20      // padded row stride for combined matrices (16B-aligned)
#define EF_DIM 64
#define BSHIFT 6     // nodes-per-bucket shift
#define NPB 64       // nodes per bucket; local id fits in 6 bits
#define NBMAX2 2048  // max buckets (N <= 131072: tail fits 17 bits)
#define CNTW 2048    // cnt table row width
#define ACCW 17      // LDS accumulator row stride (odd -> spread banks)
#define SCB 512      // scatter/hist partition blocks
// record: uint2 { local(6)[17:22] | tail(17)[0:16] , float ex }

// ---------------------------------------------------------------------------
// K0: tiny prep. Combined matrices + 8-entry edge-type logit table.
// ---------------------------------------------------------------------------
__global__ __launch_bounds__(512) void prep_kernel(
    const float* __restrict__ W, const float* __restrict__ We,
    const float* __restrict__ al, const float* __restrict__ ar,
    const float* __restrict__ ae, const float* __restrict__ emb,
    const float* __restrict__ resW,
    float* __restrict__ Wh, float* __restrict__ Wt, float* __restrict__ he,
    int NET) {
  __shared__ float v[EF_DIM];
  int t = threadIdx.x;  // 0..511 == k index
  float wl = 0.f, wr = 0.f;
#pragma unroll
  for (int c = 0; c < C_DIM; c++) {
    float wv = W[t * C_DIM + c];
    wl += wv * al[c];
    wr += wv * ar[c];
    Wt[t * MPAD + c] = wv;
    Wh[t * MPAD + c] = resW[t * C_DIM + c];
  }
  Wh[t * MPAD + C_DIM] = wl;
  Wt[t * MPAD + C_DIM] = wr;
  if (t < EF_DIM) {
    float s = 0.f;
    for (int f = 0; f < EF_DIM; f++) s += We[t * EF_DIM + f] * ae[f];
    v[t] = s;
  }
  __syncthreads();
  if (t < NET) {
    float s = 0.f;
    for (int k = 0; k < EF_DIM; k++) s += emb[t * EF_DIM + k] * v[k];
    he[t] = s;
  }
}

// ---------------------------------------------------------------------------
// K1/K2: skinny GEMM  out[N][17] = feat[N][512] @ M[512][17]
// ---------------------------------------------------------------------------
__global__ __launch_bounds__(256) void proj_kernel(
    const float* __restrict__ feat, const float* __restrict__ M,
    float* __restrict__ out16, float* __restrict__ out1, int N) {
  int r = blockIdx.x * blockDim.x + threadIdx.x;
  if (r >= N) return;
  const float4* x = (const float4*)(feat + (size_t)r * IN_F);
  float acc[CP];
#pragma unroll
  for (int c = 0; c < CP; c++) acc[c] = 0.f;
#pragma unroll 2
  for (int j = 0; j < IN_F / 4; j++) {
    float4 xv = x[j];
    const float* m0 = M + (size_t)(4 * j) * MPAD;
#pragma unroll
    for (int c = 0; c < CP; c++) acc[c] += xv.x * m0[c];
#pragma unroll
    for (int c = 0; c < CP; c++) acc[c] += xv.y * m0[MPAD + c];
#pragma unroll
    for (int c = 0; c < CP; c++) acc[c] += xv.z * m0[2 * MPAD + c];
#pragma unroll
    for (int c = 0; c < CP; c++) acc[c] += xv.w * m0[3 * MPAD + c];
  }
  float4* o = (float4*)(out16 + (size_t)r * C_DIM);
  o[0] = make_float4(acc[0], acc[1], acc[2], acc[3]);
  o[1] = make_float4(acc[4], acc[5], acc[6], acc[7]);
  o[2] = make_float4(acc[8], acc[9], acc[10], acc[11]);
  o[3] = make_float4(acc[12], acc[13], acc[14], acc[15]);
  out1[r] = acc[16];
}

// ---------------------------------------------------------------------------
// K3: per-(block,bucket) histogram -> plain 2D table (NO global atomics).
// ---------------------------------------------------------------------------
__global__ __launch_bounds__(512) void hist_kernel(
    const int* __restrict__ head, unsigned* __restrict__ cnt, int E, int NB,
    int chunk) {
  __shared__ unsigned lcnt[NBMAX2];
  int tid = threadIdx.x;
  for (int b = tid; b < NB; b += 512) lcnt[b] = 0u;
  __syncthreads();
  int start = blockIdx.x * chunk;
  int end = min(E, start + chunk);
  for (int i = start + tid; i < end; i += 512)
    atomicAdd(&lcnt[((unsigned)head[i]) >> BSHIFT], 1u);
  __syncthreads();
  unsigned* row = cnt + (size_t)blockIdx.x * CNTW;
  for (int b = tid; b < NB; b += 512) row[b] = lcnt[b];
}

// ---------------------------------------------------------------------------
// K4a: column scan. Thread b turns cnt[*][b] into per-block exclusive
// offsets and writes the bucket total. Coalesced across threads; unroll
// keeps 8 loads in flight.
// ---------------------------------------------------------------------------
__global__ __launch_bounds__(256) void colscan_kernel(
    unsigned* __restrict__ cnt, unsigned* __restrict__ btotal, int NB) {
  int b = blockIdx.x * 256 + threadIdx.x;
  if (b >= NB) return;
  unsigned running = 0;
#pragma unroll 8
  for (int blk = 0; blk < SCB; blk++) {
    unsigned v = cnt[(size_t)blk * CNTW + b];
    cnt[(size_t)blk * CNTW + b] = running;
    running += v;
  }
  btotal[b] = running;
}

// ---------------------------------------------------------------------------
// K4b: exclusive scan of bucket totals (<=2048, one block).
// ---------------------------------------------------------------------------
__global__ __launch_bounds__(1024) void scan_kernel(
    const unsigned* __restrict__ btotal, unsigned* __restrict__ base, int NB) {
  __shared__ unsigned ps[1024];
  int t = threadIdx.x;
  unsigned a = (2 * t < NB) ? btotal[2 * t] : 0u;
  unsigned b = (2 * t + 1 < NB) ? btotal[2 * t + 1] : 0u;
  ps[t] = a + b;
  __syncthreads();
  for (int off = 1; off < 1024; off <<= 1) {
    unsigned v = (t >= off) ? ps[t - off] : 0u;
    __syncthreads();
    ps[t] += v;
    __syncthreads();
  }
  unsigned excl = ps[t] - (a + b);
  if (2 * t < NB) base[2 * t] = excl;
  if (2 * t + 1 < NB) base[2 * t + 1] = excl + a;
  if (t == 1023) base[NB] = ps[1023];
}

// ---------------------------------------------------------------------------
// K5: scatter. Computes the FULL per-edge scalar chain (gather h_l,h_r,
// he; leaky-relu; exp) while streaming, and writes an 8-byte record
// {local|tail, ex}. Slot = precomputed (block,bucket) base + LDS cursor.
// ---------------------------------------------------------------------------
__global__ __launch_bounds__(512) void scatter_kernel(
    const int* __restrict__ head, const int* __restrict__ tail,
    const int* __restrict__ ty, const float* __restrict__ h_l,
    const float* __restrict__ h_r, const float* __restrict__ he_tab,
    const unsigned* __restrict__ cnt, const unsigned* __restrict__ bbase,
    uint2* __restrict__ rec, int E, int NB, int chunk, int NET) {
  __shared__ unsigned lbase[NBMAX2];
  __shared__ unsigned lcnt[NBMAX2];
  __shared__ float he_s[32];
  int tid = threadIdx.x;
  if (tid < NET) he_s[tid] = he_tab[tid];
  const unsigned* row = cnt + (size_t)blockIdx.x * CNTW;
  for (int b = tid; b < NB; b += 512) {
    lbase[b] = bbase[b] + row[b];
    lcnt[b] = 0u;
  }
  __syncthreads();
  int start = blockIdx.x * chunk;
  int end = min(E, start + chunk);
  for (int i = start + tid; i < end; i += 512) {
    unsigned h = (unsigned)head[i];
    int tl = tail[i];
    int t = ty[i];
    float lg = h_l[h] + h_r[tl] + he_s[t];
    lg = lg > 0.f ? lg : 0.2f * lg;
    float ex = __expf(lg);
    unsigned b = h >> BSHIFT;
    unsigned off = atomicAdd(&lcnt[b], 1u);
    rec[lbase[b] + off] =
        make_uint2(((h & 63u) << 17) | (unsigned)tl, __float_as_uint(ex));
  }
}

// ---------------------------------------------------------------------------
// K6: aggregation, ONE EDGE PER LANE. Per 64 edges: 1 coalesced rec load +
// 4 float4 gathers per lane (same 64B line -> L1) + 17 ds_add. Fused
// finalize (divide, residual, L2-norm, softmax-16).
// ---------------------------------------------------------------------------
__global__ __launch_bounds__(256) void agg_kernel(
    const uint2* __restrict__ rec, const unsigned* __restrict__ base,
    const float* __restrict__ ht, const float* __restrict__ resid,
    const float* __restrict__ resb, float* __restrict__ out, int N) {
  __shared__ float acc[NPB * ACCW];
  int tid = threadIdx.x;
  for (int i = tid; i < NPB * ACCW; i += 256) acc[i] = 0.f;
  __syncthreads();
  int b = blockIdx.x;
  int s = (int)base[b];
  int e = (int)base[b + 1];
  for (int i = s + tid; i < e; i += 256) {
    uint2 r = rec[i];
    int local = (int)(r.x >> 17);
    int tl = (int)(r.x & 0x1FFFFu);
    float ex = __uint_as_float(r.y);
    const float4* hp = (const float4*)(ht + (size_t)tl * C_DIM);
    float4 v0 = hp[0], v1 = hp[1], v2 = hp[2], v3 = hp[3];
    float* a = acc + local * ACCW;
    atomicAdd(a + 0, ex * v0.x);
    atomicAdd(a + 1, ex * v0.y);
    atomicAdd(a + 2, ex * v0.z);
    atomicAdd(a + 3, ex * v0.w);
    atomicAdd(a + 4, ex * v1.x);
    atomicAdd(a + 5, ex * v1.y);
    atomicAdd(a + 6, ex * v1.z);
    atomicAdd(a + 7, ex * v1.w);
    atomicAdd(a + 8, ex * v2.x);
    atomicAdd(a + 9, ex * v2.y);
    atomicAdd(a + 10, ex * v2.z);
    atomicAdd(a + 11, ex * v2.w);
    atomicAdd(a + 12, ex * v3.x);
    atomicAdd(a + 13, ex * v3.y);
    atomicAdd(a + 14, ex * v3.z);
    atomicAdd(a + 15, ex * v3.w);
    atomicAdd(a + 16, ex);
  }
  __syncthreads();
  if (tid >= NPB) return;
  int node = (b << BSHIFT) + tid;
  if (node >= N) return;
  float d = acc[tid * ACCW + 16];
  float inv = d > 0.f ? 1.f / d : 0.f;
  const float4* r4 = (const float4*)(resid + (size_t)node * C_DIM);
  float o[C_DIM];
  float ss = 0.f;
#pragma unroll
  for (int q = 0; q < 4; q++) {
    float4 rr = r4[q];
    o[4 * q + 0] = acc[tid * ACCW + 4 * q + 0] * inv + rr.x + resb[4 * q + 0];
    o[4 * q + 1] = acc[tid * ACCW + 4 * q + 1] * inv + rr.y + resb[4 * q + 1];
    o[4 * q + 2] = acc[tid * ACCW + 4 * q + 2] * inv + rr.z + resb[4 * q + 2];
    o[4 * q + 3] = acc[tid * ACCW + 4 * q + 3] * inv + rr.w + resb[4 * q + 3];
  }
#pragma unroll
  for (int cc = 0; cc < C_DIM; cc++) ss += o[cc] * o[cc];
  float sc = 1.f / fmaxf(sqrtf(ss), 1e-12f);
  float mx = -1e30f;
#pragma unroll
  for (int cc = 0; cc < C_DIM; cc++) {
    o[cc] *= sc;
    mx = fmaxf(mx, o[cc]);
  }
  float sum = 0.f;
#pragma unroll
  for (int cc = 0; cc < C_DIM; cc++) {
    o[cc] = __expf(o[cc] - mx);
    sum += o[cc];
  }
  float isum = 1.f / sum;
  float4* o4 = (float4*)(out + (size_t)node * C_DIM);
#pragma unroll
  for (int q = 0; q < 4; q++)
    o4[q] = make_float4(o[4 * q] * isum, o[4 * q + 1] * isum,
                        o[4 * q + 2] * isum, o[4 * q + 3] * isum);
}

// ---------------------------------------------------------------------------
extern "C" void kernel_launch(void* const* d_in, const int* in_sizes, int n_in,
                              void* d_out, int out_size, void* d_ws,
                              size_t ws_size, hipStream_t stream) {
  const float* head_feature = (const float*)d_in[0];
  const float* tail_feature = (const float*)d_in[1];
  const int* edge_index = (const int*)d_in[2];
  const int* tmp_edge = (const int*)d_in[3];
  const float* W = (const float*)d_in[4];
  const float* We = (const float*)d_in[5];
  const float* al = (const float*)d_in[6];
  const float* ar = (const float*)d_in[7];
  const float* ae = (const float*)d_in[8];
  const float* emb = (const float*)d_in[9];
  const float* resW = (const float*)d_in[10];
  const float* resb = (const float*)d_in[11];

  const int C = in_sizes[6];           // 16
  const int IN = in_sizes[4] / C;      // 512
  const int N = in_sizes[0] / IN;      // 100000
  const int E = in_sizes[3];           // 3200000
  const int EF = in_sizes[8];          // 64
  const int NET = in_sizes[9] / EF;    // 8
  const int NB = (N + NPB - 1) / NPB;  // 1563
  (void)C; (void)IN; (void)EF; (void)ws_size; (void)out_size; (void)n_in;

  const int* head = edge_index;
  const int* tail = edge_index + E;

  float* ws = (float*)d_ws;
  float* Wh = ws;                          // 512*20
  float* Wt = Wh + IN_F * MPAD;            // 512*20
  float* he = Wt + IN_F * MPAD;            // 32
  float* h_l = he + 32;                    // N
  float* h_r = h_l + N;                    // N
  float* ht = h_r + N;                     // 16N (64B-aligned rows)
  float* resid = ht + (size_t)C_DIM * N;   // 16N
  uint2* rec = (uint2*)(resid + (size_t)C_DIM * N);  // E (8B each)
  unsigned* cnt = (unsigned*)(rec + E);    // SCB*CNTW
  unsigned* btotal = cnt + (size_t)SCB * CNTW;  // NBMAX2
  unsigned* bbase = btotal + NBMAX2;       // NBMAX2+1

  prep_kernel<<<1, 512, 0, stream>>>(W, We, al, ar, ae, emb, resW, Wh, Wt, he,
                                     NET);
  int nb = (N + 255) / 256;
  proj_kernel<<<nb, 256, 0, stream>>>(head_feature, Wh, resid, h_l, N);
  proj_kernel<<<nb, 256, 0, stream>>>(tail_feature, Wt, ht, h_r, N);

  int chunk = (E + SCB - 1) / SCB;
  hist_kernel<<<SCB, 512, 0, stream>>>(head, cnt, E, NB, chunk);
  colscan_kernel<<<(NB + 255) / 256, 256, 0, stream>>>(cnt, btotal, NB);
  scan_kernel<<<1, 1024, 0, stream>>>(btotal, bbase, NB);
  scatter_kernel<<<SCB, 512, 0, stream>>>(head, tail, tmp_edge, h_l, h_r, he,
                                          cnt, bbase, rec, E, NB, chunk, NET);
  agg_kernel<<<NB, 256, 0, stream>>>(rec, bbase, ht, resid, resb,
                                     (float*)d_out, N);
}